// Round 11
// baseline (1244.059 us; speedup 1.0000x reference)
//
#include <hip/hip_runtime.h>
#include <math.h>

#define NTOT 16384
#define NPT  4096
#define KNN  12
#define KSEL 16           // per-chunk preselect width (margin; same metric both phases)
#define NCH  8            // candidate chunks
#define CHS  (NTOT/NCH)   // 2048
#define EPSBN 1e-5

// workspace layout, double-aligned region first, then ints
#define D_STAT 0                         // 60 doubles
#define D_COEF 60                        // 60 doubles
#define D_Y1   120
#define D_Y2   (D_Y1 + NTOT*18)
#define D_Y3   (D_Y2 + NTOT*9)
#define D_END  (D_Y3 + NTOT*3)
// part_i (ints) starts at doubles offset D_END

// ---- np-model metric: EXPANDED form, fp32, NO fma, consistent association ----
// sq  = (x*x + y*y) + z*z          (each op rounded, no fma)
// dot = (x*x' + y*y') + z*z'       (same association -> diagonal dot == sq bitwise)
// d2  = (sq_q + sq_c) - 2*dot      (2*dot exact, adds/sub rounded)
// Consequences matched: d2(i,i) == 0 exactly; extremely close pairs may round
// d2 < 0 (below self!) -> reference keeps SELF in neighbor list. We drop rank-0
// whatever it is, replicating idx[:,1:].
__device__ __forceinline__ float sq_np(float x, float y, float z) {
  return __fadd_rn(__fadd_rn(__fmul_rn(x, x), __fmul_rn(y, y)), __fmul_rn(z, z));
}
__device__ __forceinline__ float d2_np(float sqq, float qx, float qy, float qz,
                                       float sqc, float cx, float cy, float cz) {
  float dot = __fadd_rn(__fadd_rn(__fmul_rn(qx, cx), __fmul_rn(qy, cy)), __fmul_rn(qz, cz));
  return __fsub_rn(__fadd_rn(sqq, sqc), __fmul_rn(2.0f, dot));
}

// ---------------- K1: per-chunk top-16 under np-model fp32 (d2, idx) order ----------------
__global__ __launch_bounds__(256) void k_knn(const float* __restrict__ p,
                                             int* __restrict__ part_i) {
  __shared__ float4 cand[CHS];
  const int chunk = blockIdx.x & (NCH - 1);
  const int qb    = blockIdx.x >> 3;
  const int base  = chunk * CHS;
  for (int t = threadIdx.x; t < CHS; t += 256) {
    float x = p[3*(base+t)+0];
    float y = p[3*(base+t)+1];
    float z = p[3*(base+t)+2];
    cand[t] = make_float4(x, y, z, sq_np(x, y, z));
  }
  __syncthreads();
  const int q  = qb*256 + (int)threadIdx.x;
  const float qx = p[3*q+0], qy = p[3*q+1], qz = p[3*q+2];
  const float sqq = sq_np(qx, qy, qz);

  float bd[KSEL]; int bi[KSEL];
  #pragma unroll
  for (int k = 0; k < KSEL; ++k) { bd[k] = 3.4e38f; bi[k] = 0x7fffffff; }

  for (int j = 0; j < CHS; ++j) {
    float4 c = cand[j];
    float d2 = d2_np(sqq, qx, qy, qz, c.w, c.x, c.y, c.z);
    if (d2 < bd[KSEL-1]) {
      const int idx = base + j;
      // scan is idx-ascending, so strict-< insertion == stable (d2, idx) order
      #pragma unroll
      for (int k = KSEL-1; k >= 1; --k) {
        bool m1 = d2 < bd[k-1];
        bool m2 = d2 < bd[k];
        float nv = m1 ? bd[k-1] : (m2 ? d2  : bd[k]);
        int   ni = m1 ? bi[k-1] : (m2 ? idx : bi[k]);
        bd[k] = nv; bi[k] = ni;
      }
      if (d2 < bd[0]) { bd[0] = d2; bi[0] = idx; }
    }
  }
  const long o = ((long)q*NCH + chunk)*KSEL;
  #pragma unroll
  for (int k = 0; k < KSEL; ++k) part_i[o+k] = bi[k];
}

// -------- K2: re-rank 128 candidates under the SAME np-model fp32 order -> top-12 ->
//           fp64 features -> y1 (fp64), fp64 BN stats --------
__global__ __launch_bounds__(256) void k_l1(const float* __restrict__ p,
                                            const int* __restrict__ part_i,
                                            const float* __restrict__ w1,
                                            double* __restrict__ y1,
                                            double* __restrict__ stat) {
  __shared__ float w1s[18*36];
  for (int t = threadIdx.x; t < 18*36; t += 256) w1s[t] = w1[t];
  __syncthreads();
  const int q = blockIdx.x*256 + (int)threadIdx.x;
  const float qx = p[3*q+0], qy = p[3*q+1], qz = p[3*q+2];
  const float sqq = sq_np(qx, qy, qz);
  const double dqx = qx, dqy = qy, dqz = qz;

  float bd[KNN]; int bi[KNN];
  #pragma unroll
  for (int k = 0; k < KNN; ++k) { bd[k] = 3.4e38f; bi[k] = 0x7fffffff; }

  const long b0 = (long)q*NCH*KSEL;
  for (int t = 0; t < NCH*KSEL; ++t) {
    const int idx = part_i[b0 + t];
    float cx = p[3*idx+0], cy = p[3*idx+1], cz = p[3*idx+2];
    float d2 = d2_np(sqq, qx, qy, qz, sq_np(cx, cy, cz), cx, cy, cz);
    // full lexicographic (d2, idx) ascending — matches stable top_k
    bool ins = (d2 < bd[KNN-1]) || (d2 == bd[KNN-1] && idx < bi[KNN-1]);
    if (ins) {
      #pragma unroll
      for (int k = KNN-1; k >= 1; --k) {
        bool m1 = (d2 < bd[k-1]) || (d2 == bd[k-1] && idx < bi[k-1]);
        bool m2 = (d2 < bd[k])   || (d2 == bd[k]   && idx < bi[k]);
        float nv = m1 ? bd[k-1] : (m2 ? d2  : bd[k]);
        int   ni = m1 ? bi[k-1] : (m2 ? idx : bi[k]);
        bd[k] = nv; bi[k] = ni;
      }
      bool m0 = (d2 < bd[0]) || (d2 == bd[0] && idx < bi[0]);
      if (m0) { bd[0] = d2; bi[0] = idx; }
    }
  }

  // rank 0 dropped WHATEVER it is (replicates idx[:,1:]; may keep self in list
  // when a near-duplicate pair rounds d2 below 0 under the expanded metric)
  double f[36];
  f[0] = dqx; f[1] = dqy; f[2] = dqz;
  #pragma unroll
  for (int r = 0; r < KNN-1; ++r) {
    int j = bi[r+1];
    f[3 + r*3 + 0] = fabs(dqx - (double)p[3*j+0]);
    f[3 + r*3 + 1] = fabs(dqy - (double)p[3*j+1]);
    f[3 + r*3 + 2] = fabs(dqz - (double)p[3*j+2]);
  }

  double v[18];
  #pragma unroll
  for (int o = 0; o < 18; ++o) {
    double s = 0.0;
    #pragma unroll
    for (int i = 0; i < 36; ++i) s += (double)w1s[o*36+i]*f[i];
    v[o] = s;
    y1[(long)q*18 + o] = s;
  }
  #pragma unroll
  for (int o = 0; o < 18; ++o) {
    double s = v[o], ss = v[o]*v[o];
    #pragma unroll
    for (int off = 32; off > 0; off >>= 1) { s += __shfl_down(s, off); ss += __shfl_down(ss, off); }
    if ((threadIdx.x & 63) == 0) { atomicAdd(&stat[o], s); atomicAdd(&stat[18+o], ss); }
  }
}

// ---------------- finalize BN stats (fp64) -> per-channel scale/shift ----------------
__global__ void k_stats(const double* __restrict__ stat, const float* __restrict__ g,
                        const float* __restrict__ bb, double* __restrict__ coef,
                        int C, int sumoff) {
  int c = threadIdx.x;
  if (c < C) {
    const double inv = 1.0/16384.0;
    double mu   = stat[sumoff + c]*inv;
    double va   = stat[sumoff + C + c]*inv - mu*mu;
    double rstd = 1.0/sqrt(va + EPSBN);
    double a    = (double)g[c]*rstd;
    coef[c]     = a;
    coef[C + c] = (double)bb[c] - mu*a;
  }
}

// ---------------- layer 2 (fp64) ----------------
__global__ __launch_bounds__(256) void k_l2(const double* __restrict__ y1,
                                            const float* __restrict__ w2,
                                            const double* __restrict__ coef,
                                            double* __restrict__ y2,
                                            double* __restrict__ stat) {
  const int q = blockIdx.x*256 + (int)threadIdx.x;
  double h[18];
  #pragma unroll
  for (int i = 0; i < 18; ++i) {
    double t = y1[(long)q*18 + i]*coef[i] + coef[18+i];
    h[i] = t > 0.0 ? t : 0.0;
  }
  #pragma unroll
  for (int o = 0; o < 9; ++o) {
    double s = 0.0;
    #pragma unroll
    for (int i = 0; i < 18; ++i) s += (double)w2[o*18+i]*h[i];
    y2[(long)q*9 + o] = s;
    double r1 = s, r2 = s*s;
    #pragma unroll
    for (int off = 32; off > 0; off >>= 1) { r1 += __shfl_down(r1, off); r2 += __shfl_down(r2, off); }
    if ((threadIdx.x & 63) == 0) { atomicAdd(&stat[36+o], r1); atomicAdd(&stat[45+o], r2); }
  }
}

// ---------------- layer 3 (fp64) ----------------
__global__ __launch_bounds__(256) void k_l3(const double* __restrict__ y2,
                                            const float* __restrict__ w3,
                                            const double* __restrict__ coef,
                                            double* __restrict__ y3,
                                            double* __restrict__ stat) {
  const int q = blockIdx.x*256 + (int)threadIdx.x;
  double h[9];
  #pragma unroll
  for (int i = 0; i < 9; ++i) {
    double t = y2[(long)q*9 + i]*coef[i] + coef[9+i];
    h[i] = t > 0.0 ? t : 0.0;
  }
  #pragma unroll
  for (int o = 0; o < 3; ++o) {
    double s = 0.0;
    #pragma unroll
    for (int i = 0; i < 9; ++i) s += (double)w3[o*9+i]*h[i];
    y3[(long)q*3 + o] = s;
    double r1 = s, r2 = s*s;
    #pragma unroll
    for (int off = 32; off > 0; off >>= 1) { r1 += __shfl_down(r1, off); r2 += __shfl_down(r2, off); }
    if ((threadIdx.x & 63) == 0) { atomicAdd(&stat[54+o], r1); atomicAdd(&stat[57+o], r2); }
  }
}

// ---------------- head (fp64) -> fp32 out ----------------
__global__ __launch_bounds__(256) void k_out(const double* __restrict__ y3,
                                             const double* __restrict__ coef3,
                                             const float* __restrict__ wr,
                                             const float* __restrict__ br,
                                             float* __restrict__ out) {
  const int n = blockIdx.x*256 + (int)threadIdx.x;
  if (n >= NPT) return;
  double l[4];
  #pragma unroll
  for (int b = 0; b < 4; ++b) {
    long q = (long)b*NPT + n;
    double h0 = y3[q*3+0]*coef3[0] + coef3[3]; h0 = h0 > 0.0 ? h0 : 0.0;
    double h1 = y3[q*3+1]*coef3[1] + coef3[4]; h1 = h1 > 0.0 ? h1 : 0.0;
    double h2 = y3[q*3+2]*coef3[2] + coef3[5]; h2 = h2 > 0.0 ? h2 : 0.0;
    l[b] = h0*(double)wr[0] + h1*(double)wr[1] + h2*(double)wr[2] + (double)br[0];
  }
  double m = fmax(fmax(l[0], l[1]), fmax(l[2], l[3]));
  double e0 = exp(l[0]-m), e1 = exp(l[1]-m), e2 = exp(l[2]-m), e3 = exp(l[3]-m);
  double inv = 1.0/(e0+e1+e2+e3);
  out[0*NPT+n] = (float)(e0*inv);
  out[1*NPT+n] = (float)(e1*inv);
  out[2*NPT+n] = (float)(e2*inv);
  out[3*NPT+n] = (float)(e3*inv);
}

extern "C" void kernel_launch(void* const* d_in, const int* in_sizes, int n_in,
                              void* d_out, int out_size, void* d_ws, size_t ws_size,
                              hipStream_t stream) {
  const float* p  = (const float*)d_in[0];
  const float* w1 = (const float*)d_in[1];
  const float* g1 = (const float*)d_in[2];
  const float* b1 = (const float*)d_in[3];
  const float* w2 = (const float*)d_in[4];
  const float* g2 = (const float*)d_in[5];
  const float* b2 = (const float*)d_in[6];
  const float* w3 = (const float*)d_in[7];
  const float* g3 = (const float*)d_in[8];
  const float* b3 = (const float*)d_in[9];
  const float* wr = (const float*)d_in[10];
  const float* br = (const float*)d_in[11];

  double* wd    = (double*)d_ws;
  double* stat  = wd + D_STAT;
  double* coef  = wd + D_COEF;
  double* y1    = wd + D_Y1;
  double* y2    = wd + D_Y2;
  double* y3    = wd + D_Y3;
  int*    part_i= (int*)(wd + D_END);

  hipMemsetAsync(stat, 0, 60*sizeof(double), stream);

  hipLaunchKernelGGL(k_knn, dim3(NCH*(NTOT/256)), dim3(256), 0, stream, p, part_i);
  hipLaunchKernelGGL(k_l1,  dim3(NTOT/256), dim3(256), 0, stream, p, part_i, w1, y1, stat);
  hipLaunchKernelGGL(k_stats, dim3(1), dim3(32), 0, stream, stat, g1, b1, coef, 18, 0);
  hipLaunchKernelGGL(k_l2,  dim3(NTOT/256), dim3(256), 0, stream, y1, w2, coef, y2, stat);
  hipLaunchKernelGGL(k_stats, dim3(1), dim3(32), 0, stream, stat, g2, b2, coef+36, 9, 36);
  hipLaunchKernelGGL(k_l3,  dim3(NTOT/256), dim3(256), 0, stream, y2, w3, coef+36, y3, stat);
  hipLaunchKernelGGL(k_stats, dim3(1), dim3(32), 0, stream, stat, g3, b3, coef+54, 3, 54);
  hipLaunchKernelGGL(k_out, dim3(NPT/256), dim3(256), 0, stream, y3, coef+54, wr, br, (float*)d_out);
}

// Round 13
// 453.358 us; speedup vs baseline: 2.7441x; 2.7441x over previous
//
#include <hip/hip_runtime.h>
#include <math.h>

#define NTOT 16384
#define NPT  4096
#define KNN  12
#define NCH  16            // main chunks
#define CHS  (NTOT/NCH)    // 1024
#define NSMP 128           // seed samples per chunk (16*128 = 2048 samples)
#define K4   4             // seed per-chunk top-4
#define CAP  32            // per-(q,chunk) append capacity (Poisson(~6.6), +9.9 sigma)
#define EPSBN 1e-5

// doubles region first
#define D_STAT 0
#define D_COEF 60
#define D_Y1   120
#define D_Y2   (D_Y1 + NTOT*18)
#define D_Y3   (D_Y2 + NTOT*9)
#define D_END  (D_Y3 + NTOT*3)

// ---- np-model metric (validated R11): EXPANDED fp32, NO fma, consistent assoc ----
__device__ __forceinline__ float sq_np(float x, float y, float z) {
  return __fadd_rn(__fadd_rn(__fmul_rn(x, x), __fmul_rn(y, y)), __fmul_rn(z, z));
}
__device__ __forceinline__ float d2_np(float sqq, float qx, float qy, float qz,
                                       float sqc, float cx, float cy, float cz) {
  float dot = __fadd_rn(__fadd_rn(__fmul_rn(qx, cx), __fmul_rn(qy, cy)), __fmul_rn(qz, cz));
  return __fsub_rn(__fadd_rn(sqq, sqc), __fmul_rn(2.0f, dot));
}

// ---------------- K_seed: per-(q, seed-chunk) top-4 d2 over 128 samples ----------------
__global__ __launch_bounds__(256) void k_seed(const float* __restrict__ p,
                                              float* __restrict__ seedd) {
  __shared__ float4 sc[NSMP];
  const int scid = blockIdx.x & (NCH - 1);
  const int qb   = blockIdx.x >> 4;
  const int base = scid * CHS;             // samples = first 128 of each 1024-chunk
  if (threadIdx.x < NSMP) {
    int t = threadIdx.x;
    float x = p[3*(base+t)+0], y = p[3*(base+t)+1], z = p[3*(base+t)+2];
    sc[t] = make_float4(x, y, z, sq_np(x, y, z));
  }
  __syncthreads();
  const int q = qb*256 + (int)threadIdx.x;
  const float qx = p[3*q+0], qy = p[3*q+1], qz = p[3*q+2];
  const float sqq = sq_np(qx, qy, qz);

  float bd[K4];
  #pragma unroll
  for (int k = 0; k < K4; ++k) bd[k] = 3.4e38f;

  for (int j = 0; j < NSMP; ++j) {
    float4 c = sc[j];
    float d2 = d2_np(sqq, qx, qy, qz, c.w, c.x, c.y, c.z);
    if (d2 < bd[K4-1]) {
      #pragma unroll
      for (int k = K4-1; k >= 1; --k) {
        bool m1 = d2 < bd[k-1];
        bool m2 = d2 < bd[k];
        bd[k] = m1 ? bd[k-1] : (m2 ? d2 : bd[k]);
      }
      if (d2 < bd[0]) bd[0] = d2;
    }
  }
  const long o = ((long)q*NCH + scid)*K4;
  #pragma unroll
  for (int k = 0; k < K4; ++k) seedd[o+k] = bd[k];
}

// ---------------- K_thr: exact 12th-smallest of the 64 seed values -> thr[q] ----------------
// thr upper-bounds the global 12th-NN d2 (order stat of a subset >= order stat of full set).
__global__ __launch_bounds__(256) void k_thr(const float* __restrict__ seedd,
                                             float* __restrict__ thr) {
  const int q = blockIdx.x*256 + (int)threadIdx.x;
  float v[NCH*K4];
  #pragma unroll
  for (int i = 0; i < NCH*K4; ++i) v[i] = seedd[(long)q*NCH*K4 + i];
  int sel = 0; float t = 3.4e38f;
  #pragma unroll
  for (int r = 0; r < KNN; ++r) {
    if (sel < KNN) {
      float m = v[0];
      #pragma unroll
      for (int i = 1; i < NCH*K4; ++i) m = fminf(m, v[i]);
      int ce = 0;
      #pragma unroll
      for (int i = 0; i < NCH*K4; ++i) {
        bool e = (v[i] == m);
        ce += e ? 1 : 0;
        v[i] = e ? 3.4e38f : v[i];
      }
      sel += ce; t = m;
    }
  }
  thr[q] = t;
}

// ---------------- K_main: full scan, append candidates with d2 <= thr ----------------
__global__ __launch_bounds__(256) void k_main(const float* __restrict__ p,
                                              const float* __restrict__ thr,
                                              unsigned* __restrict__ gcnt,
                                              unsigned short* __restrict__ gidx) {
  __shared__ float4 mc[CHS];               // 16 KB
  const int c  = blockIdx.x & (NCH - 1);
  const int qb = blockIdx.x >> 4;
  const int base = c * CHS;
  for (int t = threadIdx.x; t < CHS; t += 256) {
    float x = p[3*(base+t)+0], y = p[3*(base+t)+1], z = p[3*(base+t)+2];
    mc[t] = make_float4(x, y, z, sq_np(x, y, z));
  }
  __syncthreads();
  const int q = qb*256 + (int)threadIdx.x;
  const float qx = p[3*q+0], qy = p[3*q+1], qz = p[3*q+2];
  const float sqq = sq_np(qx, qy, qz);
  const float tq  = thr[q];

  const long ob = ((long)q*NCH + c)*CAP;
  int cnt = 0;
  for (int j = 0; j < CHS; ++j) {
    float4 cd = mc[j];
    float d2 = d2_np(sqq, qx, qy, qz, cd.w, cd.x, cd.y, cd.z);
    if (d2 <= tq && cnt < CAP) {           // superset of true top-12 (thr >= global 12th d2)
      gidx[ob + cnt] = (unsigned short)j;  // rare (~6.6/chunk), predicated short store
      cnt++;
    }
  }
  gcnt[q*NCH + c] = (unsigned)cnt;
}

// -------- K_l1: exact re-rank of appended (~106) under np-metric -> top-12 ->
//           fp64 features -> y1 (fp64), fp64 BN stats --------
__global__ __launch_bounds__(256) void k_l1(const float* __restrict__ p,
                                            const unsigned* __restrict__ gcnt,
                                            const unsigned short* __restrict__ gidx,
                                            const float* __restrict__ w1,
                                            double* __restrict__ y1,
                                            double* __restrict__ stat) {
  __shared__ float w1s[18*36];
  for (int t = threadIdx.x; t < 18*36; t += 256) w1s[t] = w1[t];
  __syncthreads();
  const int q = blockIdx.x*256 + (int)threadIdx.x;
  const float qx = p[3*q+0], qy = p[3*q+1], qz = p[3*q+2];
  const float sqq = sq_np(qx, qy, qz);
  const double dqx = qx, dqy = qy, dqz = qz;

  float bd[KNN]; int bi[KNN];
  #pragma unroll
  for (int k = 0; k < KNN; ++k) { bd[k] = 3.4e38f; bi[k] = 0x7fffffff; }

  // stream is idx-ascending (c ascending, within-chunk ascending) -> strict-< == stable lex
  for (int c = 0; c < NCH; ++c) {
    int n = (int)gcnt[q*NCH + c]; n = n < CAP ? n : CAP;
    const long ob = ((long)q*NCH + c)*CAP;
    const int gb = c*CHS;
    for (int t = 0; t < n; ++t) {
      int idx = gb + (int)gidx[ob + t];
      float cx = p[3*idx+0], cy = p[3*idx+1], cz = p[3*idx+2];
      float d2 = d2_np(sqq, qx, qy, qz, sq_np(cx, cy, cz), cx, cy, cz);
      if (d2 < bd[KNN-1]) {
        #pragma unroll
        for (int k = KNN-1; k >= 1; --k) {
          bool m1 = d2 < bd[k-1];
          bool m2 = d2 < bd[k];
          float nv = m1 ? bd[k-1] : (m2 ? d2  : bd[k]);
          int   ni = m1 ? bi[k-1] : (m2 ? idx : bi[k]);
          bd[k] = nv; bi[k] = ni;
        }
        if (d2 < bd[0]) { bd[0] = d2; bi[0] = idx; }
      }
    }
  }

  // rank 0 dropped whatever it is (replicates idx[:,1:], incl. negative-d2 near-dupes)
  double f[36];
  f[0] = dqx; f[1] = dqy; f[2] = dqz;
  #pragma unroll
  for (int r = 0; r < KNN-1; ++r) {
    int j = bi[r+1];
    j = (j < NTOT) ? j : q;                // safety guard (never triggers: cnt >= 12 guaranteed)
    f[3 + r*3 + 0] = fabs(dqx - (double)p[3*j+0]);
    f[3 + r*3 + 1] = fabs(dqy - (double)p[3*j+1]);
    f[3 + r*3 + 2] = fabs(dqz - (double)p[3*j+2]);
  }

  double v[18];
  #pragma unroll
  for (int o = 0; o < 18; ++o) {
    double s = 0.0;
    #pragma unroll
    for (int i = 0; i < 36; ++i) s += (double)w1s[o*36+i]*f[i];
    v[o] = s;
    y1[(long)q*18 + o] = s;
  }
  #pragma unroll
  for (int o = 0; o < 18; ++o) {
    double s = v[o], ss = v[o]*v[o];
    #pragma unroll
    for (int off = 32; off > 0; off >>= 1) { s += __shfl_down(s, off); ss += __shfl_down(ss, off); }
    if ((threadIdx.x & 63) == 0) { atomicAdd(&stat[o], s); atomicAdd(&stat[18+o], ss); }
  }
}

// ---------------- finalize BN stats (fp64) -> per-channel scale/shift ----------------
__global__ void k_stats(const double* __restrict__ stat, const float* __restrict__ g,
                        const float* __restrict__ bb, double* __restrict__ coef,
                        int C, int sumoff) {
  int c = threadIdx.x;
  if (c < C) {
    const double inv = 1.0/16384.0;
    double mu   = stat[sumoff + c]*inv;
    double va   = stat[sumoff + C + c]*inv - mu*mu;
    double rstd = 1.0/sqrt(va + EPSBN);
    double a    = (double)g[c]*rstd;
    coef[c]     = a;
    coef[C + c] = (double)bb[c] - mu*a;
  }
}

// ---------------- layer 2 (fp64) ----------------
__global__ __launch_bounds__(256) void k_l2(const double* __restrict__ y1,
                                            const float* __restrict__ w2,
                                            const double* __restrict__ coef,
                                            double* __restrict__ y2,
                                            double* __restrict__ stat) {
  const int q = blockIdx.x*256 + (int)threadIdx.x;
  double h[18];
  #pragma unroll
  for (int i = 0; i < 18; ++i) {
    double t = y1[(long)q*18 + i]*coef[i] + coef[18+i];
    h[i] = t > 0.0 ? t : 0.0;
  }
  #pragma unroll
  for (int o = 0; o < 9; ++o) {
    double s = 0.0;
    #pragma unroll
    for (int i = 0; i < 18; ++i) s += (double)w2[o*18+i]*h[i];
    y2[(long)q*9 + o] = s;
    double r1 = s, r2 = s*s;
    #pragma unroll
    for (int off = 32; off > 0; off >>= 1) { r1 += __shfl_down(r1, off); r2 += __shfl_down(r2, off); }
    if ((threadIdx.x & 63) == 0) { atomicAdd(&stat[36+o], r1); atomicAdd(&stat[45+o], r2); }
  }
}

// ---------------- layer 3 (fp64) ----------------
__global__ __launch_bounds__(256) void k_l3(const double* __restrict__ y2,
                                            const float* __restrict__ w3,
                                            const double* __restrict__ coef,
                                            double* __restrict__ y3,
                                            double* __restrict__ stat) {
  const int q = blockIdx.x*256 + (int)threadIdx.x;
  double h[9];
  #pragma unroll
  for (int i = 0; i < 9; ++i) {
    double t = y2[(long)q*9 + i]*coef[i] + coef[9+i];
    h[i] = t > 0.0 ? t : 0.0;
  }
  #pragma unroll
  for (int o = 0; o < 3; ++o) {
    double s = 0.0;
    #pragma unroll
    for (int i = 0; i < 9; ++i) s += (double)w3[o*9+i]*h[i];
    y3[(long)q*3 + o] = s;
    double r1 = s, r2 = s*s;
    #pragma unroll
    for (int off = 32; off > 0; off >>= 1) { r1 += __shfl_down(r1, off); r2 += __shfl_down(r2, off); }
    if ((threadIdx.x & 63) == 0) { atomicAdd(&stat[54+o], r1); atomicAdd(&stat[57+o], r2); }
  }
}

// ---------------- head (fp64) -> fp32 out ----------------
__global__ __launch_bounds__(256) void k_out(const double* __restrict__ y3,
                                             const double* __restrict__ coef3,
                                             const float* __restrict__ wr,
                                             const float* __restrict__ br,
                                             float* __restrict__ out) {
  const int n = blockIdx.x*256 + (int)threadIdx.x;
  if (n >= NPT) return;
  double l[4];
  #pragma unroll
  for (int b = 0; b < 4; ++b) {
    long q = (long)b*NPT + n;
    double h0 = y3[q*3+0]*coef3[0] + coef3[3]; h0 = h0 > 0.0 ? h0 : 0.0;
    double h1 = y3[q*3+1]*coef3[1] + coef3[4]; h1 = h1 > 0.0 ? h1 : 0.0;
    double h2 = y3[q*3+2]*coef3[2] + coef3[5]; h2 = h2 > 0.0 ? h2 : 0.0;
    l[b] = h0*(double)wr[0] + h1*(double)wr[1] + h2*(double)wr[2] + (double)br[0];
  }
  double m = fmax(fmax(l[0], l[1]), fmax(l[2], l[3]));
  double e0 = exp(l[0]-m), e1 = exp(l[1]-m), e2 = exp(l[2]-m), e3 = exp(l[3]-m);
  double inv = 1.0/(e0+e1+e2+e3);
  out[0*NPT+n] = (float)(e0*inv);
  out[1*NPT+n] = (float)(e1*inv);
  out[2*NPT+n] = (float)(e2*inv);
  out[3*NPT+n] = (float)(e3*inv);
}

extern "C" void kernel_launch(void* const* d_in, const int* in_sizes, int n_in,
                              void* d_out, int out_size, void* d_ws, size_t ws_size,
                              hipStream_t stream) {
  const float* p  = (const float*)d_in[0];
  const float* w1 = (const float*)d_in[1];
  const float* g1 = (const float*)d_in[2];
  const float* b1 = (const float*)d_in[3];
  const float* w2 = (const float*)d_in[4];
  const float* g2 = (const float*)d_in[5];
  const float* b2 = (const float*)d_in[6];
  const float* w3 = (const float*)d_in[7];
  const float* g3 = (const float*)d_in[8];
  const float* b3 = (const float*)d_in[9];
  const float* wr = (const float*)d_in[10];
  const float* br = (const float*)d_in[11];

  double* wd   = (double*)d_ws;
  double* stat = wd + D_STAT;
  double* coef = wd + D_COEF;
  double* y1   = wd + D_Y1;
  double* y2   = wd + D_Y2;
  double* y3   = wd + D_Y3;
  float*  fb    = (float*)(wd + D_END);
  float*  seedd = fb;                                   // NTOT*NCH*K4 floats (4 MB)
  float*  thr   = seedd + (long)NTOT*NCH*K4;            // NTOT floats
  unsigned* gcnt = (unsigned*)(thr + NTOT);             // NTOT*NCH uints
  unsigned short* gidx = (unsigned short*)(gcnt + NTOT*NCH); // NTOT*NCH*CAP ushorts (16.8 MB)

  hipMemsetAsync(stat, 0, 60*sizeof(double), stream);

  hipLaunchKernelGGL(k_seed, dim3((NTOT/256)*NCH), dim3(256), 0, stream, p, seedd);
  hipLaunchKernelGGL(k_thr,  dim3(NTOT/256), dim3(256), 0, stream, seedd, thr);
  hipLaunchKernelGGL(k_main, dim3((NTOT/256)*NCH), dim3(256), 0, stream, p, thr, gcnt, gidx);
  hipLaunchKernelGGL(k_l1,   dim3(NTOT/256), dim3(256), 0, stream, p, gcnt, gidx, w1, y1, stat);
  hipLaunchKernelGGL(k_stats, dim3(1), dim3(32), 0, stream, stat, g1, b1, coef, 18, 0);
  hipLaunchKernelGGL(k_l2,   dim3(NTOT/256), dim3(256), 0, stream, y1, w2, coef, y2, stat);
  hipLaunchKernelGGL(k_stats, dim3(1), dim3(32), 0, stream, stat, g2, b2, coef+36, 9, 36);
  hipLaunchKernelGGL(k_l3,   dim3(NTOT/256), dim3(256), 0, stream, y2, w3, coef+36, y3, stat);
  hipLaunchKernelGGL(k_stats, dim3(1), dim3(32), 0, stream, stat, g3, b3, coef+54, 3, 54);
  hipLaunchKernelGGL(k_out,  dim3(NPT/256), dim3(256), 0, stream, y3, coef+54, wr, br, (float*)d_out);
}

// Round 15
// 439.773 us; speedup vs baseline: 2.8289x; 1.0309x over previous
//
#include <hip/hip_runtime.h>
#include <math.h>

#define NTOT 16384
#define NPT  4096
#define KNN  12
#define NCH  16            // main chunks
#define CHS  (NTOT/NCH)    // 1024
#define NSMP 128           // seed samples per chunk
#define K4   4             // seed per-chunk top-4
#define CAP  32            // per-(q,chunk) append capacity
#define EPSBN 1e-5

// doubles region first
#define D_STAT 0
#define D_COEF 60
#define D_Y1   120
#define D_Y2   (D_Y1 + NTOT*18)
#define D_Y3   (D_Y2 + NTOT*9)
#define D_END  (D_Y3 + NTOT*3)

// ---- np-model metric (validated R11): EXPANDED fp32, NO fma, consistent assoc ----
__device__ __forceinline__ float sq_np(float x, float y, float z) {
  return __fadd_rn(__fadd_rn(__fmul_rn(x, x), __fmul_rn(y, y)), __fmul_rn(z, z));
}
__device__ __forceinline__ float d2_np(float sqq, float qx, float qy, float qz,
                                       float sqc, float cx, float cy, float cz) {
  float dot = __fadd_rn(__fadd_rn(__fmul_rn(qx, cx), __fmul_rn(qy, cy)), __fmul_rn(qz, cz));
  return __fsub_rn(__fadd_rn(sqq, sqc), __fmul_rn(2.0f, dot));
}

// ---------------- K_seed: per-(q, seed-chunk) top-4 d2 over 128 samples ----------------
__global__ __launch_bounds__(256) void k_seed(const float* __restrict__ p,
                                              float* __restrict__ seedd) {
  __shared__ float4 sc[NSMP];
  const int scid = blockIdx.x & (NCH - 1);
  const int qb   = blockIdx.x >> 4;
  const int base = scid * CHS;
  if (threadIdx.x < NSMP) {
    int t = threadIdx.x;
    float x = p[3*(base+t)+0], y = p[3*(base+t)+1], z = p[3*(base+t)+2];
    sc[t] = make_float4(x, y, z, sq_np(x, y, z));
  }
  __syncthreads();
  const int q = qb*256 + (int)threadIdx.x;
  const float qx = p[3*q+0], qy = p[3*q+1], qz = p[3*q+2];
  const float sqq = sq_np(qx, qy, qz);

  float bd[K4];
  #pragma unroll
  for (int k = 0; k < K4; ++k) bd[k] = 3.4e38f;

  for (int j = 0; j < NSMP; ++j) {
    float4 c = sc[j];
    float d2 = d2_np(sqq, qx, qy, qz, c.w, c.x, c.y, c.z);
    if (d2 < bd[K4-1]) {
      #pragma unroll
      for (int k = K4-1; k >= 1; --k) {
        bool m1 = d2 < bd[k-1];
        bool m2 = d2 < bd[k];
        bd[k] = m1 ? bd[k-1] : (m2 ? d2 : bd[k]);
      }
      if (d2 < bd[0]) bd[0] = d2;
    }
  }
  const long o = ((long)q*NCH + scid)*K4;
  #pragma unroll
  for (int k = 0; k < K4; ++k) seedd[o+k] = bd[k];
}

// ---------------- K_thr: exact 12th-smallest of the 64 seed values -> thr[q] ----------------
__global__ __launch_bounds__(256) void k_thr(const float* __restrict__ seedd,
                                             float* __restrict__ thr) {
  const int q = blockIdx.x*256 + (int)threadIdx.x;
  float v[NCH*K4];
  #pragma unroll
  for (int i = 0; i < NCH*K4; ++i) v[i] = seedd[(long)q*NCH*K4 + i];
  int sel = 0; float t = 3.4e38f;
  #pragma unroll
  for (int r = 0; r < KNN; ++r) {
    if (sel < KNN) {
      float m = v[0];
      #pragma unroll
      for (int i = 1; i < NCH*K4; ++i) m = fminf(m, v[i]);
      int ce = 0;
      #pragma unroll
      for (int i = 0; i < NCH*K4; ++i) {
        bool e = (v[i] == m);
        ce += e ? 1 : 0;
        v[i] = e ? 3.4e38f : v[i];
      }
      sel += ce; t = m;
    }
  }
  thr[q] = t;
}

// ---------------- K_main: full scan, append (d2, idx) of candidates with d2 <= thr ----------------
__global__ __launch_bounds__(256) void k_main(const float* __restrict__ p,
                                              const float* __restrict__ thr,
                                              unsigned* __restrict__ gcnt,
                                              float* __restrict__ d2f,
                                              unsigned short* __restrict__ gidx) {
  __shared__ float4 mc[CHS];               // 16 KB
  const int c  = blockIdx.x & (NCH - 1);
  const int qb = blockIdx.x >> 4;
  const int base = c * CHS;
  for (int t = threadIdx.x; t < CHS; t += 256) {
    float x = p[3*(base+t)+0], y = p[3*(base+t)+1], z = p[3*(base+t)+2];
    mc[t] = make_float4(x, y, z, sq_np(x, y, z));
  }
  __syncthreads();
  const int q = qb*256 + (int)threadIdx.x;
  const float qx = p[3*q+0], qy = p[3*q+1], qz = p[3*q+2];
  const float sqq = sq_np(qx, qy, qz);
  const float tq  = thr[q];

  const long ob = ((long)q*NCH + c)*CAP;
  int cnt = 0;
  for (int j = 0; j < CHS; ++j) {
    float4 cd = mc[j];
    float d2 = d2_np(sqq, qx, qy, qz, cd.w, cd.x, cd.y, cd.z);
    if (d2 <= tq && cnt < CAP) {           // superset of true top-12
      d2f [ob + cnt] = d2;                 // exact np-metric value, reused in k_l1
      gidx[ob + cnt] = (unsigned short)j;
      cnt++;
    }
  }
  gcnt[q*NCH + c] = (unsigned)cnt;
}

// -------- K_l1: merge precomputed (d2, idx) streams -> top-12 ->
//           fp64 features -> y1 (fp64), fp64 BN stats --------
// 64 thr/block x 256 blocks: all CUs busy (was 64 blocks -> 2.3% occupancy, latency-bound).
__global__ __launch_bounds__(64) void k_l1(const float* __restrict__ p,
                                           const unsigned* __restrict__ gcnt,
                                           const float* __restrict__ d2f,
                                           const unsigned short* __restrict__ gidx,
                                           const float* __restrict__ w1,
                                           double* __restrict__ y1,
                                           double* __restrict__ stat) {
  __shared__ float w1s[18*36];
  for (int t = threadIdx.x; t < 18*36; t += 64) w1s[t] = w1[t];
  __syncthreads();
  const int q = blockIdx.x*64 + (int)threadIdx.x;
  const double dqx = (double)p[3*q+0], dqy = (double)p[3*q+1], dqz = (double)p[3*q+2];

  float bd[KNN]; int bi[KNN];
  #pragma unroll
  for (int k = 0; k < KNN; ++k) { bd[k] = 3.4e38f; bi[k] = 0x7fffffff; }

  // stream is idx-ascending (c asc, within-chunk asc); d2 bits identical to k_main's
  // np-metric evaluation -> strict-< insertion == stable (d2, idx) lex order
  for (int c = 0; c < NCH; ++c) {
    int n = (int)gcnt[q*NCH + c]; n = n < CAP ? n : CAP;
    const long ob = ((long)q*NCH + c)*CAP;
    const int gb = c*CHS;
    for (int t = 0; t < n; ++t) {
      float d2 = d2f[ob + t];
      int  idx = gb + (int)gidx[ob + t];
      if (d2 < bd[KNN-1]) {
        #pragma unroll
        for (int k = KNN-1; k >= 1; --k) {
          bool m1 = d2 < bd[k-1];
          bool m2 = d2 < bd[k];
          float nv = m1 ? bd[k-1] : (m2 ? d2  : bd[k]);
          int   ni = m1 ? bi[k-1] : (m2 ? idx : bi[k]);
          bd[k] = nv; bi[k] = ni;
        }
        if (d2 < bd[0]) { bd[0] = d2; bi[0] = idx; }
      }
    }
  }

  // rank 0 dropped whatever it is (replicates idx[:,1:], incl. negative-d2 near-dupes)
  double f[36];
  f[0] = dqx; f[1] = dqy; f[2] = dqz;
  #pragma unroll
  for (int r = 0; r < KNN-1; ++r) {
    int j = bi[r+1];
    j = (j < NTOT) ? j : q;                // safety guard (cnt >= 12 guaranteed)
    f[3 + r*3 + 0] = fabs(dqx - (double)p[3*j+0]);
    f[3 + r*3 + 1] = fabs(dqy - (double)p[3*j+1]);
    f[3 + r*3 + 2] = fabs(dqz - (double)p[3*j+2]);
  }

  double v[18];
  #pragma unroll
  for (int o = 0; o < 18; ++o) {
    double s = 0.0;
    #pragma unroll
    for (int i = 0; i < 36; ++i) s += (double)w1s[o*36+i]*f[i];
    v[o] = s;
    y1[(long)q*18 + o] = s;
  }
  #pragma unroll
  for (int o = 0; o < 18; ++o) {
    double s = v[o], ss = v[o]*v[o];
    #pragma unroll
    for (int off = 32; off > 0; off >>= 1) { s += __shfl_down(s, off); ss += __shfl_down(ss, off); }
    if (threadIdx.x == 0) { atomicAdd(&stat[o], s); atomicAdd(&stat[18+o], ss); }
  }
}

// ---------------- finalize BN stats (fp64) -> per-channel scale/shift ----------------
__global__ void k_stats(const double* __restrict__ stat, const float* __restrict__ g,
                        const float* __restrict__ bb, double* __restrict__ coef,
                        int C, int sumoff) {
  int c = threadIdx.x;
  if (c < C) {
    const double inv = 1.0/16384.0;
    double mu   = stat[sumoff + c]*inv;
    double va   = stat[sumoff + C + c]*inv - mu*mu;
    double rstd = 1.0/sqrt(va + EPSBN);
    double a    = (double)g[c]*rstd;
    coef[c]     = a;
    coef[C + c] = (double)bb[c] - mu*a;
  }
}

// ---------------- layer 2 (fp64) ----------------
__global__ __launch_bounds__(256) void k_l2(const double* __restrict__ y1,
                                            const float* __restrict__ w2,
                                            const double* __restrict__ coef,
                                            double* __restrict__ y2,
                                            double* __restrict__ stat) {
  const int q = blockIdx.x*256 + (int)threadIdx.x;
  double h[18];
  #pragma unroll
  for (int i = 0; i < 18; ++i) {
    double t = y1[(long)q*18 + i]*coef[i] + coef[18+i];
    h[i] = t > 0.0 ? t : 0.0;
  }
  #pragma unroll
  for (int o = 0; o < 9; ++o) {
    double s = 0.0;
    #pragma unroll
    for (int i = 0; i < 18; ++i) s += (double)w2[o*18+i]*h[i];
    y2[(long)q*9 + o] = s;
    double r1 = s, r2 = s*s;
    #pragma unroll
    for (int off = 32; off > 0; off >>= 1) { r1 += __shfl_down(r1, off); r2 += __shfl_down(r2, off); }
    if ((threadIdx.x & 63) == 0) { atomicAdd(&stat[36+o], r1); atomicAdd(&stat[45+o], r2); }
  }
}

// ---------------- layer 3 (fp64) ----------------
__global__ __launch_bounds__(256) void k_l3(const double* __restrict__ y2,
                                            const float* __restrict__ w3,
                                            const double* __restrict__ coef,
                                            double* __restrict__ y3,
                                            double* __restrict__ stat) {
  const int q = blockIdx.x*256 + (int)threadIdx.x;
  double h[9];
  #pragma unroll
  for (int i = 0; i < 9; ++i) {
    double t = y2[(long)q*9 + i]*coef[i] + coef[9+i];
    h[i] = t > 0.0 ? t : 0.0;
  }
  #pragma unroll
  for (int o = 0; o < 3; ++o) {
    double s = 0.0;
    #pragma unroll
    for (int i = 0; i < 9; ++i) s += (double)w3[o*9+i]*h[i];
    y3[(long)q*3 + o] = s;
    double r1 = s, r2 = s*s;
    #pragma unroll
    for (int off = 32; off > 0; off >>= 1) { r1 += __shfl_down(r1, off); r2 += __shfl_down(r2, off); }
    if ((threadIdx.x & 63) == 0) { atomicAdd(&stat[54+o], r1); atomicAdd(&stat[57+o], r2); }
  }
}

// ---------------- head (fp64) -> fp32 out ----------------
__global__ __launch_bounds__(256) void k_out(const double* __restrict__ y3,
                                             const double* __restrict__ coef3,
                                             const float* __restrict__ wr,
                                             const float* __restrict__ br,
                                             float* __restrict__ out) {
  const int n = blockIdx.x*256 + (int)threadIdx.x;
  if (n >= NPT) return;
  double l[4];
  #pragma unroll
  for (int b = 0; b < 4; ++b) {
    long q = (long)b*NPT + n;
    double h0 = y3[q*3+0]*coef3[0] + coef3[3]; h0 = h0 > 0.0 ? h0 : 0.0;
    double h1 = y3[q*3+1]*coef3[1] + coef3[4]; h1 = h1 > 0.0 ? h1 : 0.0;
    double h2 = y3[q*3+2]*coef3[2] + coef3[5]; h2 = h2 > 0.0 ? h2 : 0.0;
    l[b] = h0*(double)wr[0] + h1*(double)wr[1] + h2*(double)wr[2] + (double)br[0];
  }
  double m = fmax(fmax(l[0], l[1]), fmax(l[2], l[3]));
  double e0 = exp(l[0]-m), e1 = exp(l[1]-m), e2 = exp(l[2]-m), e3 = exp(l[3]-m);
  double inv = 1.0/(e0+e1+e2+e3);
  out[0*NPT+n] = (float)(e0*inv);
  out[1*NPT+n] = (float)(e1*inv);
  out[2*NPT+n] = (float)(e2*inv);
  out[3*NPT+n] = (float)(e3*inv);
}

extern "C" void kernel_launch(void* const* d_in, const int* in_sizes, int n_in,
                              void* d_out, int out_size, void* d_ws, size_t ws_size,
                              hipStream_t stream) {
  const float* p  = (const float*)d_in[0];
  const float* w1 = (const float*)d_in[1];
  const float* g1 = (const float*)d_in[2];
  const float* b1 = (const float*)d_in[3];
  const float* w2 = (const float*)d_in[4];
  const float* g2 = (const float*)d_in[5];
  const float* b2 = (const float*)d_in[6];
  const float* w3 = (const float*)d_in[7];
  const float* g3 = (const float*)d_in[8];
  const float* b3 = (const float*)d_in[9];
  const float* wr = (const float*)d_in[10];
  const float* br = (const float*)d_in[11];

  double* wd   = (double*)d_ws;
  double* stat = wd + D_STAT;
  double* coef = wd + D_COEF;
  double* y1   = wd + D_Y1;
  double* y2   = wd + D_Y2;
  double* y3   = wd + D_Y3;
  float*  fb    = (float*)(wd + D_END);
  float*  seedd = fb;                                        // NTOT*NCH*K4 floats (4 MB)
  float*  thr   = seedd + (long)NTOT*NCH*K4;                 // NTOT floats
  unsigned* gcnt = (unsigned*)(thr + NTOT);                  // NTOT*NCH uints (1 MB)
  float*  d2f   = (float*)(gcnt + NTOT*NCH);                 // NTOT*NCH*CAP floats (33.5 MB)
  unsigned short* gidx = (unsigned short*)(d2f + (long)NTOT*NCH*CAP); // 16.8 MB

  hipMemsetAsync(stat, 0, 60*sizeof(double), stream);

  hipLaunchKernelGGL(k_seed, dim3((NTOT/256)*NCH), dim3(256), 0, stream, p, seedd);
  hipLaunchKernelGGL(k_thr,  dim3(NTOT/256), dim3(256), 0, stream, seedd, thr);
  hipLaunchKernelGGL(k_main, dim3((NTOT/256)*NCH), dim3(256), 0, stream, p, thr, gcnt, d2f, gidx);
  hipLaunchKernelGGL(k_l1,   dim3(NTOT/64), dim3(64), 0, stream, p, gcnt, d2f, gidx, w1, y1, stat);
  hipLaunchKernelGGL(k_stats, dim3(1), dim3(32), 0, stream, stat, g1, b1, coef, 18, 0);
  hipLaunchKernelGGL(k_l2,   dim3(NTOT/256), dim3(256), 0, stream, y1, w2, coef, y2, stat);
  hipLaunchKernelGGL(k_stats, dim3(1), dim3(32), 0, stream, stat, g2, b2, coef+36, 9, 36);
  hipLaunchKernelGGL(k_l3,   dim3(NTOT/256), dim3(256), 0, stream, y2, w3, coef+36, y3, stat);
  hipLaunchKernelGGL(k_stats, dim3(1), dim3(32), 0, stream, stat, g3, b3, coef+54, 3, 54);
  hipLaunchKernelGGL(k_out,  dim3(NPT/256), dim3(256), 0, stream, y3, coef+54, wr, br, (float*)d_out);
}

// Round 17
// 427.479 us; speedup vs baseline: 2.9102x; 1.0288x over previous
//
#include <hip/hip_runtime.h>
#include <math.h>

#define NTOT 16384
#define NPT  4096
#define KNN  12
#define NCH  16            // main chunks
#define CHS  (NTOT/NCH)    // 1024
#define NSMP 128           // seed samples per chunk
#define K4   4             // seed per-chunk top-4
#define CAP  32            // per-(q,chunk) append capacity
#define EPSBN 1e-5

// doubles region first
#define D_STAT 0
#define D_COEF 60
#define D_Y1   120
#define D_Y2   (D_Y1 + NTOT*18)
#define D_Y3   (D_Y2 + NTOT*9)
#define D_END  (D_Y3 + NTOT*3)

// ---- np-model metric (validated R11): EXPANDED fp32, NO fma, consistent assoc ----
__device__ __forceinline__ float sq_np(float x, float y, float z) {
  return __fadd_rn(__fadd_rn(__fmul_rn(x, x), __fmul_rn(y, y)), __fmul_rn(z, z));
}
__device__ __forceinline__ float d2_np(float sqq, float qx, float qy, float qz,
                                       float sqc, float cx, float cy, float cz) {
  float dot = __fadd_rn(__fadd_rn(__fmul_rn(qx, cx), __fmul_rn(qy, cy)), __fmul_rn(qz, cz));
  return __fsub_rn(__fadd_rn(sqq, sqc), __fmul_rn(2.0f, dot));
}

// ---------------- K_seed: per-(q, seed-chunk) top-4 d2 over 128 samples ----------------
__global__ __launch_bounds__(256) void k_seed(const float* __restrict__ p,
                                              float* __restrict__ seedd) {
  __shared__ float4 sc[NSMP];
  const int scid = blockIdx.x & (NCH - 1);
  const int qb   = blockIdx.x >> 4;
  const int base = scid * CHS;
  if (threadIdx.x < NSMP) {
    int t = threadIdx.x;
    float x = p[3*(base+t)+0], y = p[3*(base+t)+1], z = p[3*(base+t)+2];
    sc[t] = make_float4(x, y, z, sq_np(x, y, z));
  }
  __syncthreads();
  const int q = qb*256 + (int)threadIdx.x;
  const float qx = p[3*q+0], qy = p[3*q+1], qz = p[3*q+2];
  const float sqq = sq_np(qx, qy, qz);

  float bd[K4];
  #pragma unroll
  for (int k = 0; k < K4; ++k) bd[k] = 3.4e38f;

  for (int j = 0; j < NSMP; ++j) {
    float4 c = sc[j];
    float d2 = d2_np(sqq, qx, qy, qz, c.w, c.x, c.y, c.z);
    if (d2 < bd[K4-1]) {
      #pragma unroll
      for (int k = K4-1; k >= 1; --k) {
        bool m1 = d2 < bd[k-1];
        bool m2 = d2 < bd[k];
        bd[k] = m1 ? bd[k-1] : (m2 ? d2 : bd[k]);
      }
      if (d2 < bd[0]) bd[0] = d2;
    }
  }
  const long o = ((long)q*NCH + scid)*K4;
  #pragma unroll
  for (int k = 0; k < K4; ++k) seedd[o+k] = bd[k];
}

// ---------------- K_thr: exact 12th-smallest of the 64 seed values -> thr[q] ----------------
__global__ __launch_bounds__(256) void k_thr(const float* __restrict__ seedd,
                                             float* __restrict__ thr) {
  const int q = blockIdx.x*256 + (int)threadIdx.x;
  float v[NCH*K4];
  #pragma unroll
  for (int i = 0; i < NCH*K4; ++i) v[i] = seedd[(long)q*NCH*K4 + i];
  int sel = 0; float t = 3.4e38f;
  #pragma unroll
  for (int r = 0; r < KNN; ++r) {
    if (sel < KNN) {
      float m = v[0];
      #pragma unroll
      for (int i = 1; i < NCH*K4; ++i) m = fminf(m, v[i]);
      int ce = 0;
      #pragma unroll
      for (int i = 0; i < NCH*K4; ++i) {
        bool e = (v[i] == m);
        ce += e ? 1 : 0;
        v[i] = e ? 3.4e38f : v[i];
      }
      sel += ce; t = m;
    }
  }
  thr[q] = t;
}

// ---------------- K_main: full scan, append (d2, idx) of candidates with d2 <= thr ----------------
__global__ __launch_bounds__(256) void k_main(const float* __restrict__ p,
                                              const float* __restrict__ thr,
                                              unsigned* __restrict__ gcnt,
                                              float* __restrict__ d2f,
                                              unsigned short* __restrict__ gidx) {
  __shared__ float4 mc[CHS];               // 16 KB
  const int c  = blockIdx.x & (NCH - 1);
  const int qb = blockIdx.x >> 4;
  const int base = c * CHS;
  for (int t = threadIdx.x; t < CHS; t += 256) {
    float x = p[3*(base+t)+0], y = p[3*(base+t)+1], z = p[3*(base+t)+2];
    mc[t] = make_float4(x, y, z, sq_np(x, y, z));
  }
  __syncthreads();
  const int q = qb*256 + (int)threadIdx.x;
  const float qx = p[3*q+0], qy = p[3*q+1], qz = p[3*q+2];
  const float sqq = sq_np(qx, qy, qz);
  const float tq  = thr[q];

  const long ob = ((long)q*NCH + c)*CAP;
  int cnt = 0;
  for (int j = 0; j < CHS; ++j) {
    float4 cd = mc[j];
    float d2 = d2_np(sqq, qx, qy, qz, cd.w, cd.x, cd.y, cd.z);
    if (d2 <= tq && cnt < CAP) {           // superset of true top-12
      d2f [ob + cnt] = d2;                 // exact np-metric value
      gidx[ob + cnt] = (unsigned short)j;
      cnt++;
    }
  }
  gcnt[q*NCH + c] = (unsigned)cnt;
}

// ---------------- K_sel: wave-group-parallel 12-round min-extraction ----------------
// 16 lanes per query (lane = chunk). 262144 threads = 4096 waves = 16/CU (vs 256 waves before).
// Lex (d2, idx) order via orderable-float uint64 keys -> selection identical to stable top_k.
__global__ __launch_bounds__(256) void k_sel(const unsigned* __restrict__ gcnt,
                                             const float* __restrict__ d2f,
                                             const unsigned short* __restrict__ gidx,
                                             int* __restrict__ nbr) {
  const int grp  = (int)threadIdx.x >> 4;
  const int lane = (int)threadIdx.x & 15;  // chunk id
  const int q    = blockIdx.x*16 + grp;
  const int slot = q*NCH + lane;
  int n = (int)gcnt[slot]; n = n < CAP ? n : CAP;
  const long ob = (long)slot*CAP;
  unsigned consumed = 0;

  #pragma unroll
  for (int r = 0; r < KNN; ++r) {
    float mind = 3.4e38f; int tmin = -1;
    for (int t = 0; t < n; ++t) {
      float d = d2f[ob + t];
      bool ok = (((consumed >> t) & 1u) == 0u) && (d < mind);
      mind = ok ? d : mind;
      tmin = ok ? t : tmin;
    }
    unsigned long long key = 0xFFFFFFFFFFFFFFFFull;
    if (tmin >= 0) {
      unsigned u = __float_as_uint(mind);
      u = (u & 0x80000000u) ? ~u : (u | 0x80000000u);   // orderable: handles d2<0 near-dupes
      unsigned gi = (unsigned)(lane*CHS) + (unsigned)gidx[ob + tmin];
      key = ((unsigned long long)u << 32) | gi;
    }
    unsigned long long kmin = key;
    #pragma unroll
    for (int m = 1; m < 16; m <<= 1) {
      unsigned long long o = __shfl_xor(kmin, m);
      kmin = (o < kmin) ? o : kmin;
    }
    if (key == kmin && tmin >= 0) consumed |= (1u << tmin);   // unique idx -> unique winner
    if (lane == 0 && r > 0)                                   // rank 0 dropped (idx[:,1:])
      nbr[q*(KNN-1) + (r-1)] = (int)(unsigned)(kmin & 0xFFFFFFFFull);
  }
}

// -------- K_feat: nbr -> fp64 features -> y1 = W1 f (fp64), fp64 BN stats --------
__global__ __launch_bounds__(256) void k_feat(const float* __restrict__ p,
                                              const int* __restrict__ nbr,
                                              const float* __restrict__ w1,
                                              double* __restrict__ y1,
                                              double* __restrict__ stat) {
  __shared__ float w1s[18*36];
  for (int t = threadIdx.x; t < 18*36; t += 256) w1s[t] = w1[t];
  __syncthreads();
  const int q = blockIdx.x*256 + (int)threadIdx.x;
  const double dqx = (double)p[3*q+0], dqy = (double)p[3*q+1], dqz = (double)p[3*q+2];

  double f[36];
  f[0] = dqx; f[1] = dqy; f[2] = dqz;
  #pragma unroll
  for (int r = 0; r < KNN-1; ++r) {
    int j = nbr[q*(KNN-1) + r];
    f[3 + r*3 + 0] = fabs(dqx - (double)p[3*j+0]);
    f[3 + r*3 + 1] = fabs(dqy - (double)p[3*j+1]);
    f[3 + r*3 + 2] = fabs(dqz - (double)p[3*j+2]);
  }

  double v[18];
  #pragma unroll
  for (int o = 0; o < 18; ++o) {
    double s = 0.0;
    #pragma unroll
    for (int i = 0; i < 36; ++i) s += (double)w1s[o*36+i]*f[i];
    v[o] = s;
    y1[(long)q*18 + o] = s;
  }
  #pragma unroll
  for (int o = 0; o < 18; ++o) {
    double s = v[o], ss = v[o]*v[o];
    #pragma unroll
    for (int off = 32; off > 0; off >>= 1) { s += __shfl_down(s, off); ss += __shfl_down(ss, off); }
    if ((threadIdx.x & 63) == 0) { atomicAdd(&stat[o], s); atomicAdd(&stat[18+o], ss); }
  }
}

// ---------------- finalize BN stats (fp64) -> per-channel scale/shift ----------------
__global__ void k_stats(const double* __restrict__ stat, const float* __restrict__ g,
                        const float* __restrict__ bb, double* __restrict__ coef,
                        int C, int sumoff) {
  int c = threadIdx.x;
  if (c < C) {
    const double inv = 1.0/16384.0;
    double mu   = stat[sumoff + c]*inv;
    double va   = stat[sumoff + C + c]*inv - mu*mu;
    double rstd = 1.0/sqrt(va + EPSBN);
    double a    = (double)g[c]*rstd;
    coef[c]     = a;
    coef[C + c] = (double)bb[c] - mu*a;
  }
}

// ---------------- layer 2 (fp64) ----------------
__global__ __launch_bounds__(256) void k_l2(const double* __restrict__ y1,
                                            const float* __restrict__ w2,
                                            const double* __restrict__ coef,
                                            double* __restrict__ y2,
                                            double* __restrict__ stat) {
  const int q = blockIdx.x*256 + (int)threadIdx.x;
  double h[18];
  #pragma unroll
  for (int i = 0; i < 18; ++i) {
    double t = y1[(long)q*18 + i]*coef[i] + coef[18+i];
    h[i] = t > 0.0 ? t : 0.0;
  }
  #pragma unroll
  for (int o = 0; o < 9; ++o) {
    double s = 0.0;
    #pragma unroll
    for (int i = 0; i < 18; ++i) s += (double)w2[o*18+i]*h[i];
    y2[(long)q*9 + o] = s;
    double r1 = s, r2 = s*s;
    #pragma unroll
    for (int off = 32; off > 0; off >>= 1) { r1 += __shfl_down(r1, off); r2 += __shfl_down(r2, off); }
    if ((threadIdx.x & 63) == 0) { atomicAdd(&stat[36+o], r1); atomicAdd(&stat[45+o], r2); }
  }
}

// ---------------- layer 3 (fp64) ----------------
__global__ __launch_bounds__(256) void k_l3(const double* __restrict__ y2,
                                            const float* __restrict__ w3,
                                            const double* __restrict__ coef,
                                            double* __restrict__ y3,
                                            double* __restrict__ stat) {
  const int q = blockIdx.x*256 + (int)threadIdx.x;
  double h[9];
  #pragma unroll
  for (int i = 0; i < 9; ++i) {
    double t = y2[(long)q*9 + i]*coef[i] + coef[9+i];
    h[i] = t > 0.0 ? t : 0.0;
  }
  #pragma unroll
  for (int o = 0; o < 3; ++o) {
    double s = 0.0;
    #pragma unroll
    for (int i = 0; i < 9; ++i) s += (double)w3[o*9+i]*h[i];
    y3[(long)q*3 + o] = s;
    double r1 = s, r2 = s*s;
    #pragma unroll
    for (int off = 32; off > 0; off >>= 1) { r1 += __shfl_down(r1, off); r2 += __shfl_down(r2, off); }
    if ((threadIdx.x & 63) == 0) { atomicAdd(&stat[54+o], r1); atomicAdd(&stat[57+o], r2); }
  }
}

// ---------------- head (fp64) -> fp32 out ----------------
__global__ __launch_bounds__(256) void k_out(const double* __restrict__ y3,
                                             const double* __restrict__ coef3,
                                             const float* __restrict__ wr,
                                             const float* __restrict__ br,
                                             float* __restrict__ out) {
  const int n = blockIdx.x*256 + (int)threadIdx.x;
  if (n >= NPT) return;
  double l[4];
  #pragma unroll
  for (int b = 0; b < 4; ++b) {
    long q = (long)b*NPT + n;
    double h0 = y3[q*3+0]*coef3[0] + coef3[3]; h0 = h0 > 0.0 ? h0 : 0.0;
    double h1 = y3[q*3+1]*coef3[1] + coef3[4]; h1 = h1 > 0.0 ? h1 : 0.0;
    double h2 = y3[q*3+2]*coef3[2] + coef3[5]; h2 = h2 > 0.0 ? h2 : 0.0;
    l[b] = h0*(double)wr[0] + h1*(double)wr[1] + h2*(double)wr[2] + (double)br[0];
  }
  double m = fmax(fmax(l[0], l[1]), fmax(l[2], l[3]));
  double e0 = exp(l[0]-m), e1 = exp(l[1]-m), e2 = exp(l[2]-m), e3 = exp(l[3]-m);
  double inv = 1.0/(e0+e1+e2+e3);
  out[0*NPT+n] = (float)(e0*inv);
  out[1*NPT+n] = (float)(e1*inv);
  out[2*NPT+n] = (float)(e2*inv);
  out[3*NPT+n] = (float)(e3*inv);
}

extern "C" void kernel_launch(void* const* d_in, const int* in_sizes, int n_in,
                              void* d_out, int out_size, void* d_ws, size_t ws_size,
                              hipStream_t stream) {
  const float* p  = (const float*)d_in[0];
  const float* w1 = (const float*)d_in[1];
  const float* g1 = (const float*)d_in[2];
  const float* b1 = (const float*)d_in[3];
  const float* w2 = (const float*)d_in[4];
  const float* g2 = (const float*)d_in[5];
  const float* b2 = (const float*)d_in[6];
  const float* w3 = (const float*)d_in[7];
  const float* g3 = (const float*)d_in[8];
  const float* b3 = (const float*)d_in[9];
  const float* wr = (const float*)d_in[10];
  const float* br = (const float*)d_in[11];

  double* wd   = (double*)d_ws;
  double* stat = wd + D_STAT;
  double* coef = wd + D_COEF;
  double* y1   = wd + D_Y1;
  double* y2   = wd + D_Y2;
  double* y3   = wd + D_Y3;
  float*  fb    = (float*)(wd + D_END);
  float*  seedd = fb;                                        // NTOT*NCH*K4 floats (4 MB)
  float*  thr   = seedd + (long)NTOT*NCH*K4;                 // NTOT floats
  unsigned* gcnt = (unsigned*)(thr + NTOT);                  // NTOT*NCH uints (1 MB)
  float*  d2f   = (float*)(gcnt + NTOT*NCH);                 // NTOT*NCH*CAP floats (33.5 MB)
  unsigned short* gidx = (unsigned short*)(d2f + (long)NTOT*NCH*CAP); // 16.8 MB
  int*    nbr   = (int*)seedd;                               // aliases seedd (dead after k_thr)

  hipMemsetAsync(stat, 0, 60*sizeof(double), stream);

  hipLaunchKernelGGL(k_seed, dim3((NTOT/256)*NCH), dim3(256), 0, stream, p, seedd);
  hipLaunchKernelGGL(k_thr,  dim3(NTOT/256), dim3(256), 0, stream, seedd, thr);
  hipLaunchKernelGGL(k_main, dim3((NTOT/256)*NCH), dim3(256), 0, stream, p, thr, gcnt, d2f, gidx);
  hipLaunchKernelGGL(k_sel,  dim3(NTOT/16), dim3(256), 0, stream, gcnt, d2f, gidx, nbr);
  hipLaunchKernelGGL(k_feat, dim3(NTOT/256), dim3(256), 0, stream, p, nbr, w1, y1, stat);
  hipLaunchKernelGGL(k_stats, dim3(1), dim3(32), 0, stream, stat, g1, b1, coef, 18, 0);
  hipLaunchKernelGGL(k_l2,   dim3(NTOT/256), dim3(256), 0, stream, y1, w2, coef, y2, stat);
  hipLaunchKernelGGL(k_stats, dim3(1), dim3(32), 0, stream, stat, g2, b2, coef+36, 9, 36);
  hipLaunchKernelGGL(k_l3,   dim3(NTOT/256), dim3(256), 0, stream, y2, w3, coef+36, y3, stat);
  hipLaunchKernelGGL(k_stats, dim3(1), dim3(32), 0, stream, stat, g3, b3, coef+54, 3, 54);
  hipLaunchKernelGGL(k_out,  dim3(NPT/256), dim3(256), 0, stream, y3, coef+54, wr, br, (float*)d_out);
}